// Round 6
// baseline (198.355 us; speedup 1.0000x reference)
//
#include <hip/hip_runtime.h>
#include <hip/hip_bf16.h>
#include <hip/hip_cooperative_groups.h>

namespace cg = cooperative_groups;

#define NG     2048
#define HW     128
#define NPIX   (HW*HW)
#define SEG    16
#define CHUNK  (NG/SEG)   // 128
#define GPB    (NG/256)   // 8 gaussians per block (merged kernel)
#define NEARZ  0.3f
#define GEPS   1e-4f
#define LOG2E  1.4426950408889634f

// ---- sorted gaussian tables (device globals; rewritten every call) -------
__device__ float4   g_ga_s[NG];  // u, v, A, B   (conic pre-scaled by -0.5*log2e)
__device__ float4   g_gb_s[NG];  // C, opa_masked, cr, cg
__device__ float    g_cb_s[NG];
__device__ unsigned g_bb_s[NG];  // packed AABB: ymin<<24|ymax<<16|xmin<<8|xmax

__device__ __forceinline__ float sigm(float x) { return 1.0f / (1.0f + __expf(-x)); }

__device__ __forceinline__ bool detect_f32(const void* rot) {
    return ((const unsigned short*)rot)[1] != 0;   // rot[0][1]==0 exactly
}
__device__ __forceinline__ float ld(const void* p, int idx, bool f32) {
    if (f32) return ((const float*)p)[idx];
    return __bfloat162float(((const __hip_bfloat16*)p)[idx]);
}

// ---- shared phase implementations ----------------------------------------

// Full conic preprocess for gaussian i; scatter to sorted slot rk.
__device__ __forceinline__ void prep_one(int i, int rk, bool f32,
                                         const float* R, const float* T3,
                                         const void* pos, const void* rgb,
                                         const void* opa, const void* quat,
                                         const void* scale)
{
    float p0 = ld(pos, i*3+0, f32), p1 = ld(pos, i*3+1, f32), p2 = ld(pos, i*3+2, f32);
    float x = R[0]*p0 + R[1]*p1 + R[2]*p2 + T3[0];
    float y = R[3]*p0 + R[4]*p1 + R[5]*p2 + T3[1];
    float z = R[6]*p0 + R[7]*p1 + R[8]*p2 + T3[2];
    float iz = 1.0f / z;
    float u = x * iz, v = y * iz;

    float qw = ld(quat, i*4+0, f32), qx = ld(quat, i*4+1, f32);
    float qy = ld(quat, i*4+2, f32), qz = ld(quat, i*4+3, f32);
    float qn = 1.0f / sqrtf(qw*qw + qx*qx + qy*qy + qz*qz);
    qw *= qn; qx *= qn; qy *= qn; qz *= qn;
    float Rm[3][3];
    Rm[0][0] = 1.0f - 2.0f*(qy*qy + qz*qz);
    Rm[0][1] = 2.0f*(qx*qy - qw*qz);
    Rm[0][2] = 2.0f*(qx*qz + qw*qy);
    Rm[1][0] = 2.0f*(qx*qy + qw*qz);
    Rm[1][1] = 1.0f - 2.0f*(qx*qx + qz*qz);
    Rm[1][2] = 2.0f*(qy*qz - qw*qx);
    Rm[2][0] = 2.0f*(qx*qz - qw*qy);
    Rm[2][1] = 2.0f*(qy*qz + qw*qx);
    Rm[2][2] = 1.0f - 2.0f*(qx*qx + qy*qy);

    float s[3];
    #pragma unroll
    for (int k = 0; k < 3; k++) s[k] = fabsf(ld(scale, i*3+k, f32)) + 1e-4f;

    float RS[3][3];
    #pragma unroll
    for (int a = 0; a < 3; a++)
        #pragma unroll
        for (int b = 0; b < 3; b++) RS[a][b] = Rm[a][b] * s[b];
    float C3[3][3];
    #pragma unroll
    for (int a = 0; a < 3; a++)
        #pragma unroll
        for (int b = 0; b < 3; b++)
            C3[a][b] = RS[a][0]*RS[b][0] + RS[a][1]*RS[b][1] + RS[a][2]*RS[b][2];

    float nx = -x * iz * iz, ny = -y * iz * iz;
    float jw0[3], jw1[3];
    #pragma unroll
    for (int k = 0; k < 3; k++) {
        jw0[k] = iz * R[0*3+k] + nx * R[2*3+k];
        jw1[k] = iz * R[1*3+k] + ny * R[2*3+k];
    }
    float t0[3], t1[3];
    #pragma unroll
    for (int j = 0; j < 3; j++) {
        t0[j] = C3[j][0]*jw0[0] + C3[j][1]*jw0[1] + C3[j][2]*jw0[2];
        t1[j] = C3[j][0]*jw1[0] + C3[j][1]*jw1[1] + C3[j][2]*jw1[2];
    }
    float a = jw0[0]*t0[0] + jw0[1]*t0[1] + jw0[2]*t0[2] + GEPS;
    float b = jw0[0]*t1[0] + jw0[1]*t1[1] + jw0[2]*t1[2];
    float c = jw1[0]*t1[0] + jw1[1]*t1[1] + jw1[2]*t1[2] + GEPS;
    float det  = a*c - b*b;
    float idet = 1.0f / det;
    float Af = -0.5f * LOG2E * (c * idet);
    float Bf = -LOG2E * (-b * idet);
    float Cf = -0.5f * LOG2E * (a * idet);

    float om = (z > NEARZ) ? sigm(ld(opa, i, f32)) : 0.0f;
    float cr = sigm(ld(rgb, i*3+0, f32));
    float cg = sigm(ld(rgb, i*3+1, f32));
    float cb = sigm(ld(rgb, i*3+2, f32));

    // conservative AABB: |d| > 6.5*sqrt(lam_max) => alpha < e^-21 (lossless)
    float mid = 0.5f * (a + c);
    float lam = mid + sqrtf(fmaxf(mid*mid - det, 0.0f));
    float rad = 6.5f * sqrtf(lam) * 128.0f;
    float u_px = u * 128.0f + 63.5f;
    float v_px = v * 128.0f + 63.5f;
    unsigned bb = 0xFF00FF00u;
    if (om > 0.0f) {
        int ymn = (int)ceilf (v_px - rad);
        int ymx = (int)floorf(v_px + rad);
        int xmn = (int)ceilf (u_px - rad);
        int xmx = (int)floorf(u_px + rad);
        if (ymx >= 0 && ymn <= 127 && xmx >= 0 && xmn <= 127) {
            ymn = max(ymn, 0); ymx = min(ymx, 127);
            xmn = max(xmn, 0); xmx = min(xmx, 127);
            bb = (unsigned)((ymn << 24) | (ymx << 16) | (xmn << 8) | xmx);
        }
    }

    g_ga_s[rk] = make_float4(u, v, Af, Bf);
    g_gb_s[rk] = make_float4(Cf, om, cr, cg);
    g_cb_s[rk] = cb;
    g_bb_s[rk] = bb;
}

// Raster phase body: one 64-px strip per block, ballot culling, LDS combine.
__device__ __forceinline__ void raster_body(int strip, int tid,
                                            float4* comb,
                                            void* out, bool f32)
{
    int lane = tid & 63;
    int w    = __builtin_amdgcn_readfirstlane(tid >> 6);

    int pix = strip * 64 + lane;
    int row = strip >> 1;
    int x0  = (strip & 1) * 64;
    int x1  = x0 + 63;
    int col = x0 + lane;
    float pxf = (col - 63.5f) * (1.0f / 128.0f);
    float pyf = (row - 63.5f) * (1.0f / 128.0f);

    float T = 1.0f, Cr = 0.0f, Cg = 0.0f, Cb = 0.0f;
    int base = w * CHUNK;

    #pragma unroll
    for (int c = 0; c < CHUNK / 64; c++) {
        int cbase = base + c * 64;
        unsigned bb = g_bb_s[cbase + lane];
        int ymn =  bb >> 24;
        int ymx = (bb >> 16) & 255;
        int xmn = (bb >>  8) & 255;
        int xmx =  bb        & 255;
        bool hit = (row >= ymn) & (row <= ymx) & (x1 >= xmn) & (x0 <= xmx);
        unsigned long long m = __ballot(hit);
        while (m) {
            int kk = __builtin_ctzll(m);
            m &= m - 1;
            int idx = cbase + kk;
            float4 a4 = g_ga_s[idx];
            float4 b4 = g_gb_s[idx];
            float  cc = g_cb_s[idx];
            float dx = pxf - a4.x;
            float dy = pyf - a4.y;
            float p  = (a4.z * dx + a4.w * dy) * dx;
            p = fmaf(b4.x * dy, dy, p);
            float alpha = fminf(b4.y * __builtin_amdgcn_exp2f(p), 0.99f);
            float wgt = T * alpha;
            Cr = fmaf(wgt, b4.z, Cr);
            Cg = fmaf(wgt, b4.w, Cg);
            Cb = fmaf(wgt, cc, Cb);
            T -= wgt;
        }
    }

    comb[w * 64 + lane] = make_float4(T, Cr, Cg, Cb);
    __syncthreads();

    if (tid < 64) {
        float Ta = 1.0f, Ra = 0.0f, Ga = 0.0f, Ba = 0.0f;
        #pragma unroll
        for (int s = 0; s < SEG; s++) {
            float4 c4 = comb[s * 64 + lane];
            Ra = fmaf(Ta, c4.y, Ra);
            Ga = fmaf(Ta, c4.z, Ga);
            Ba = fmaf(Ta, c4.w, Ba);
            Ta *= c4.x;
        }
        if (f32) {
            float* o = (float*)out;
            o[pix*3 + 0] = Ra; o[pix*3 + 1] = Ga; o[pix*3 + 2] = Ba;
        } else {
            __hip_bfloat16* o = (__hip_bfloat16*)out;
            o[pix*3 + 0] = __float2bfloat16(Ra);
            o[pix*3 + 1] = __float2bfloat16(Ga);
            o[pix*3 + 2] = __float2bfloat16(Ba);
        }
    }
}

// ---------------------------------------------------------------------------
// Merged cooperative kernel: 256 blocks x 1024 threads (1 block/CU).
// Phase 1: prep+sort (block owns 8 gaussians)  -> grid.sync -> Phase 2: raster.
// ---------------------------------------------------------------------------
__global__ __launch_bounds__(1024, 4)
void splat_coop_kernel(void* __restrict__ out,
                       const void* __restrict__ pos,
                       const void* __restrict__ rgb,
                       const void* __restrict__ opa,
                       const void* __restrict__ quat,
                       const void* __restrict__ scale,
                       const void* __restrict__ rot,
                       const void* __restrict__ tran)
{
    __shared__ float  rs[NG];
    __shared__ int    srank[GPB];
    __shared__ float4 comb[SEG * 64];

    int tid = threadIdx.x;
    bool f32 = detect_f32(rot);

    float R[9], T3[3];
    #pragma unroll
    for (int k = 0; k < 9; k++) R[k] = ld(rot, k, f32);
    #pragma unroll
    for (int k = 0; k < 3; k++) T3[k] = ld(tran, k, f32);

    // ---- Phase 1A: all 2048 sort keys into LDS (2 per thread) ----
    #pragma unroll
    for (int k = 0; k < NG / 1024; k++) {
        int j = tid + k * 1024;
        float p0 = ld(pos, j*3+0, f32), p1 = ld(pos, j*3+1, f32), p2 = ld(pos, j*3+2, f32);
        float x = R[0]*p0 + R[1]*p1 + R[2]*p2 + T3[0];
        float y = R[3]*p0 + R[4]*p1 + R[5]*p2 + T3[1];
        float z = R[6]*p0 + R[7]*p1 + R[8]*p2 + T3[2];
        rs[j] = sqrtf(x*x + y*y + z*z);
    }
    __syncthreads();

    // ---- Phase 1B: rank the block's 8 gaussians (1 wave each) ----
    if (tid < GPB * 64) {
        int g    = blockIdx.x * GPB + (tid >> 6);   // wave-uniform gaussian
        int lane = tid & 63;
        float ri = rs[g];
        int rank = 0;
        int jbase = lane * (NG / 64);               // 32-key slice
        #pragma unroll 8
        for (int jj = 0; jj < NG / 64; jj++) {
            int j = jbase + ((jj + lane) & (NG / 64 - 1));  // 2-way banks: free
            float rj = rs[j];
            rank += (rj < ri) || (rj == ri && j < g);       // argsort-stable
        }
        #pragma unroll
        for (int d = 1; d < 64; d <<= 1) rank += __shfl_xor(rank, d);
        if (lane == 0) srank[tid >> 6] = rank;
    }
    __syncthreads();

    // ---- Phase 1C: full prep for 8 owned gaussians, scatter sorted ----
    if (tid < GPB) {
        int i = blockIdx.x * GPB + tid;
        prep_one(i, srank[tid], f32, R, T3, pos, rgb, opa, quat, scale);
    }

    // ---- grid-wide sync (device-scope visibility for the tables) ----
    __threadfence();
    cg::this_grid().sync();

    // ---- Phase 2: raster (block = strip) ----
    raster_body(blockIdx.x, tid, comb, out, f32);
}

// ---------------------------------------------------------------------------
// Fallback path: the proven R5 two-kernel pipeline (used only if the
// cooperative launch is rejected by the runtime/capture).
// ---------------------------------------------------------------------------
__global__ __launch_bounds__(256)
void prep_sort_kernel(const void* __restrict__ pos,
                      const void* __restrict__ rgb,
                      const void* __restrict__ opa,
                      const void* __restrict__ quat,
                      const void* __restrict__ scale,
                      const void* __restrict__ rot,
                      const void* __restrict__ tran)
{
    __shared__ float rs[NG];
    __shared__ int   srank[16];

    int tid = threadIdx.x;
    bool f32 = detect_f32(rot);

    float R[9], T3[3];
    #pragma unroll
    for (int k = 0; k < 9; k++) R[k] = ld(rot, k, f32);
    #pragma unroll
    for (int k = 0; k < 3; k++) T3[k] = ld(tran, k, f32);

    #pragma unroll
    for (int k = 0; k < NG / 256; k++) {
        int j = tid + k * 256;
        float p0 = ld(pos, j*3+0, f32), p1 = ld(pos, j*3+1, f32), p2 = ld(pos, j*3+2, f32);
        float x = R[0]*p0 + R[1]*p1 + R[2]*p2 + T3[0];
        float y = R[3]*p0 + R[4]*p1 + R[5]*p2 + T3[1];
        float z = R[6]*p0 + R[7]*p1 + R[8]*p2 + T3[2];
        rs[j] = sqrtf(x*x + y*y + z*z);
    }
    __syncthreads();

    int g      = blockIdx.x * 16 + (tid >> 4);
    int lane16 = tid & 15;
    float ri = rs[g];
    int rank = 0;
    int jbase = lane16 * CHUNK;
    #pragma unroll 4
    for (int jj = 0; jj < CHUNK; jj++) {
        int j = jbase + ((jj + 2 * lane16) & (CHUNK - 1));
        float rj = rs[j];
        rank += (rj < ri) || (rj == ri && j < g);
    }
    #pragma unroll
    for (int d = 1; d < 16; d <<= 1) rank += __shfl_xor(rank, d);
    if (lane16 == 0) srank[tid >> 4] = rank;
    __syncthreads();

    if (tid < 16) {
        int i = blockIdx.x * 16 + tid;
        prep_one(i, srank[tid], f32, R, T3, pos, rgb, opa, quat, scale);
    }
}

__global__ __launch_bounds__(1024)
void raster_kernel(void* __restrict__ out, const void* __restrict__ rot)
{
    __shared__ float4 comb[SEG * 64];
    raster_body(blockIdx.x, threadIdx.x, comb, out, detect_f32(rot));
}

// ---------------------------------------------------------------------------
extern "C" void kernel_launch(void* const* d_in, const int* in_sizes, int n_in,
                              void* d_out, int out_size, void* d_ws, size_t ws_size,
                              hipStream_t stream)
{
    const void* pos   = d_in[0];
    const void* rgb   = d_in[1];
    const void* opa   = d_in[2];
    const void* quat  = d_in[3];
    const void* scale = d_in[4];
    const void* rot   = d_in[5];
    const void* tran  = d_in[6];
    void* out = d_out;

    void* args[] = { &out, (void*)&pos, (void*)&rgb, (void*)&opa, (void*)&quat,
                     (void*)&scale, (void*)&rot, (void*)&tran };
    hipError_t err = hipLaunchCooperativeKernel(
        reinterpret_cast<const void*>(splat_coop_kernel),
        dim3(NPIX / 64), dim3(1024), args, 0, stream);

    if (err != hipSuccess) {
        // proven two-kernel fallback
        prep_sort_kernel<<<NG/16, 256, 0, stream>>>(pos, rgb, opa, quat, scale, rot, tran);
        raster_kernel<<<NPIX/64, 1024, 0, stream>>>(d_out, rot);
    }
}

// Round 7
// 90.076 us; speedup vs baseline: 2.2021x; 2.2021x over previous
//
#include <hip/hip_runtime.h>
#include <hip/hip_bf16.h>

#define NG     2048
#define HW     128
#define NPIX   (HW*HW)
#define SEG    16
#define CHUNK  (NG/SEG)   // 128
#define NEARZ  0.3f
#define GEPS   1e-4f
#define LOG2E  1.4426950408889634f

// ---- sorted gaussian tables (device globals; rewritten every call) -------
__device__ float4   g_ga_s[NG];  // u, v, A, B   (conic pre-scaled by -0.5*log2e)
__device__ float4   g_gb_s[NG];  // C, opa_masked, cr, cg
__device__ float    g_cb_s[NG];
__device__ unsigned g_bb_s[NG];  // packed AABB: ymin<<24|ymax<<16|xmin<<8|xmax

__device__ __forceinline__ float sigm(float x) { return 1.0f / (1.0f + __expf(-x)); }

// dtype discriminator (inputs proven f32 in R2; kept for safety):
// rot[0][1]==0.0 exactly -> 16-bit word #1 is 0x0000 for bf16, 0x3F7F for f32.
__device__ __forceinline__ bool detect_f32(const void* rot) {
    return ((const unsigned short*)rot)[1] != 0;
}
__device__ __forceinline__ float ld(const void* p, int idx, bool f32) {
    if (f32) return ((const float*)p)[idx];
    return __bfloat162float(((const __hip_bfloat16*)p)[idx]);
}

// ---------------------------------------------------------------------------
// Kernel 1: fused preprocess + stable rank sort + AABB computation.
// 128 blocks x 256 threads (16 gaussians/block).
// NOTE (R6): do NOT merge these two kernels via cooperative grid.sync —
// measured ~100us barrier cost on gfx950 (8 non-coherent XCDs) vs ~2us
// for a plain kernel boundary.
// ---------------------------------------------------------------------------
__global__ __launch_bounds__(256)
void prep_sort_kernel(const void* __restrict__ pos,
                      const void* __restrict__ rgb,
                      const void* __restrict__ opa,
                      const void* __restrict__ quat,
                      const void* __restrict__ scale,
                      const void* __restrict__ rot,
                      const void* __restrict__ tran)
{
    __shared__ float rs[NG];
    __shared__ int   srank[16];

    int tid = threadIdx.x;
    bool f32 = detect_f32(rot);

    float R[9], T3[3];
    #pragma unroll
    for (int k = 0; k < 9; k++) R[k] = ld(rot, k, f32);
    #pragma unroll
    for (int k = 0; k < 3; k++) T3[k] = ld(tran, k, f32);

    // ---- A: sort keys for all gaussians ----
    #pragma unroll
    for (int k = 0; k < NG / 256; k++) {
        int j = tid + k * 256;
        float p0 = ld(pos, j*3+0, f32), p1 = ld(pos, j*3+1, f32), p2 = ld(pos, j*3+2, f32);
        float x = R[0]*p0 + R[1]*p1 + R[2]*p2 + T3[0];
        float y = R[3]*p0 + R[4]*p1 + R[5]*p2 + T3[1];
        float z = R[6]*p0 + R[7]*p1 + R[8]*p2 + T3[2];
        rs[j] = sqrtf(x*x + y*y + z*z);
    }
    __syncthreads();

    // ---- B: rank the block's 16 gaussians (16 lanes each) ----
    int g      = blockIdx.x * 16 + (tid >> 4);
    int lane16 = tid & 15;
    float ri = rs[g];
    int rank = 0;
    int jbase = lane16 * CHUNK;
    #pragma unroll 4
    for (int jj = 0; jj < CHUNK; jj++) {
        int j = jbase + ((jj + 2 * lane16) & (CHUNK - 1));
        float rj = rs[j];
        rank += (rj < ri) || (rj == ri && j < g);           // argsort-stable
    }
    #pragma unroll
    for (int d = 1; d < 16; d <<= 1) rank += __shfl_xor(rank, d);
    if (lane16 == 0) srank[tid >> 4] = rank;
    __syncthreads();

    // ---- C: full preprocess for 16 owned gaussians, scatter sorted ----
    if (tid < 16) {
        int i  = blockIdx.x * 16 + tid;
        int rk = srank[tid];

        float p0 = ld(pos, i*3+0, f32), p1 = ld(pos, i*3+1, f32), p2 = ld(pos, i*3+2, f32);
        float x = R[0]*p0 + R[1]*p1 + R[2]*p2 + T3[0];
        float y = R[3]*p0 + R[4]*p1 + R[5]*p2 + T3[1];
        float z = R[6]*p0 + R[7]*p1 + R[8]*p2 + T3[2];
        float iz = 1.0f / z;
        float u = x * iz, v = y * iz;

        float qw = ld(quat, i*4+0, f32), qx = ld(quat, i*4+1, f32);
        float qy = ld(quat, i*4+2, f32), qz = ld(quat, i*4+3, f32);
        float qn = 1.0f / sqrtf(qw*qw + qx*qx + qy*qy + qz*qz);
        qw *= qn; qx *= qn; qy *= qn; qz *= qn;
        float Rm[3][3];
        Rm[0][0] = 1.0f - 2.0f*(qy*qy + qz*qz);
        Rm[0][1] = 2.0f*(qx*qy - qw*qz);
        Rm[0][2] = 2.0f*(qx*qz + qw*qy);
        Rm[1][0] = 2.0f*(qx*qy + qw*qz);
        Rm[1][1] = 1.0f - 2.0f*(qx*qx + qz*qz);
        Rm[1][2] = 2.0f*(qy*qz - qw*qx);
        Rm[2][0] = 2.0f*(qx*qz - qw*qy);
        Rm[2][1] = 2.0f*(qy*qz + qw*qx);
        Rm[2][2] = 1.0f - 2.0f*(qx*qx + qy*qy);

        float s[3];
        #pragma unroll
        for (int k = 0; k < 3; k++) s[k] = fabsf(ld(scale, i*3+k, f32)) + 1e-4f;

        float RS[3][3];
        #pragma unroll
        for (int a = 0; a < 3; a++)
            #pragma unroll
            for (int b = 0; b < 3; b++) RS[a][b] = Rm[a][b] * s[b];
        float C3[3][3];
        #pragma unroll
        for (int a = 0; a < 3; a++)
            #pragma unroll
            for (int b = 0; b < 3; b++)
                C3[a][b] = RS[a][0]*RS[b][0] + RS[a][1]*RS[b][1] + RS[a][2]*RS[b][2];

        float nx = -x * iz * iz, ny = -y * iz * iz;
        float jw0[3], jw1[3];
        #pragma unroll
        for (int k = 0; k < 3; k++) {
            jw0[k] = iz * R[0*3+k] + nx * R[2*3+k];
            jw1[k] = iz * R[1*3+k] + ny * R[2*3+k];
        }
        float t0[3], t1[3];
        #pragma unroll
        for (int j = 0; j < 3; j++) {
            t0[j] = C3[j][0]*jw0[0] + C3[j][1]*jw0[1] + C3[j][2]*jw0[2];
            t1[j] = C3[j][0]*jw1[0] + C3[j][1]*jw1[1] + C3[j][2]*jw1[2];
        }
        float a = jw0[0]*t0[0] + jw0[1]*t0[1] + jw0[2]*t0[2] + GEPS;
        float b = jw0[0]*t1[0] + jw0[1]*t1[1] + jw0[2]*t1[2];
        float c = jw1[0]*t1[0] + jw1[1]*t1[1] + jw1[2]*t1[2] + GEPS;
        float det  = a*c - b*b;
        float idet = 1.0f / det;
        float Af = -0.5f * LOG2E * (c * idet);
        float Bf = -LOG2E * (-b * idet);
        float Cf = -0.5f * LOG2E * (a * idet);

        float om = (z > NEARZ) ? sigm(ld(opa, i, f32)) : 0.0f;
        float cr = sigm(ld(rgb, i*3+0, f32));
        float cg = sigm(ld(rgb, i*3+1, f32));
        float cb = sigm(ld(rgb, i*3+2, f32));

        // conservative AABB: |d| > 6.5*sqrt(lam_max)  =>  alpha < e^-21
        float mid = 0.5f * (a + c);
        float lam = mid + sqrtf(fmaxf(mid*mid - det, 0.0f));
        float rad = 6.5f * sqrtf(lam) * 128.0f;     // pixels
        float u_px = u * 128.0f + 63.5f;
        float v_px = v * 128.0f + 63.5f;
        unsigned bb = 0xFF00FF00u;                  // "never hits" sentinel
        if (om > 0.0f) {
            int ymn = (int)ceilf (v_px - rad);
            int ymx = (int)floorf(v_px + rad);
            int xmn = (int)ceilf (u_px - rad);
            int xmx = (int)floorf(u_px + rad);
            if (ymx >= 0 && ymn <= 127 && xmx >= 0 && xmn <= 127) {
                ymn = max(ymn, 0); ymx = min(ymx, 127);
                xmn = max(xmn, 0); xmx = min(xmx, 127);
                bb = (unsigned)((ymn << 24) | (ymx << 16) | (xmn << 8) | xmx);
            }
        }

        g_ga_s[rk] = make_float4(u, v, Af, Bf);
        g_gb_s[rk] = make_float4(Cf, om, cr, cg);
        g_cb_s[rk] = cb;
        g_bb_s[rk] = bb;
    }
}

// ---------------------------------------------------------------------------
// Kernel 2: rasterize with ballot culling.
// 256 blocks x 1024 threads. Block = 64-px row strip (row uniform).
// Wave w owns sorted segment w; 64 lanes vector-test 64 AABBs, ballot,
// then ctz-walk survivors (ascending => front-to-back order preserved).
// ---------------------------------------------------------------------------
__global__ __launch_bounds__(1024)
void raster_kernel(void* __restrict__ out, const void* __restrict__ rot)
{
    __shared__ float4 comb[SEG * 64];

    int tid  = threadIdx.x;
    int lane = tid & 63;
    int w    = __builtin_amdgcn_readfirstlane(tid >> 6);

    int pix = blockIdx.x * 64 + lane;
    int row = blockIdx.x >> 1;          // uniform per block
    int x0  = (blockIdx.x & 1) * 64;    // uniform strip start
    int x1  = x0 + 63;
    int col = x0 + lane;
    float pxf = (col - 63.5f) * (1.0f / 128.0f);
    float pyf = (row - 63.5f) * (1.0f / 128.0f);

    float T = 1.0f, Cr = 0.0f, Cg = 0.0f, Cb = 0.0f;
    int base = w * CHUNK;

    #pragma unroll
    for (int c = 0; c < CHUNK / 64; c++) {          // 2 chunks of 64
        int cbase = base + c * 64;
        unsigned bb = g_bb_s[cbase + lane];          // coalesced vector load
        int ymn =  bb >> 24;
        int ymx = (bb >> 16) & 255;
        int xmn = (bb >>  8) & 255;
        int xmx =  bb        & 255;
        bool hit = (row >= ymn) & (row <= ymx) & (x1 >= xmn) & (x0 <= xmx);
        unsigned long long m = __ballot(hit);
        while (m) {
            int kk = __builtin_ctzll(m);
            m &= m - 1;
            int idx = cbase + kk;                    // uniform index
            float4 a4 = g_ga_s[idx];
            float4 b4 = g_gb_s[idx];
            float  cc = g_cb_s[idx];
            float dx = pxf - a4.x;
            float dy = pyf - a4.y;
            float p  = (a4.z * dx + a4.w * dy) * dx;
            p = fmaf(b4.x * dy, dy, p);              // log2-domain, NSD
            float alpha = fminf(b4.y * __builtin_amdgcn_exp2f(p), 0.99f);
            float wgt = T * alpha;
            Cr = fmaf(wgt, b4.z, Cr);
            Cg = fmaf(wgt, b4.w, Cg);
            Cb = fmaf(wgt, cc, Cb);
            T -= wgt;                                // T *= (1-alpha)
        }
    }

    comb[w * 64 + lane] = make_float4(T, Cr, Cg, Cb);
    __syncthreads();

    if (tid < 64) {
        float Ta = 1.0f, Ra = 0.0f, Ga = 0.0f, Ba = 0.0f;
        #pragma unroll
        for (int s = 0; s < SEG; s++) {
            float4 c4 = comb[s * 64 + lane];
            Ra = fmaf(Ta, c4.y, Ra);
            Ga = fmaf(Ta, c4.z, Ga);
            Ba = fmaf(Ta, c4.w, Ba);
            Ta *= c4.x;
        }
        if (detect_f32(rot)) {
            float* o = (float*)out;
            o[pix*3 + 0] = Ra; o[pix*3 + 1] = Ga; o[pix*3 + 2] = Ba;
        } else {
            __hip_bfloat16* o = (__hip_bfloat16*)out;
            o[pix*3 + 0] = __float2bfloat16(Ra);
            o[pix*3 + 1] = __float2bfloat16(Ga);
            o[pix*3 + 2] = __float2bfloat16(Ba);
        }
    }
}

// ---------------------------------------------------------------------------
extern "C" void kernel_launch(void* const* d_in, const int* in_sizes, int n_in,
                              void* d_out, int out_size, void* d_ws, size_t ws_size,
                              hipStream_t stream)
{
    const void* pos   = d_in[0];
    const void* rgb   = d_in[1];
    const void* opa   = d_in[2];
    const void* quat  = d_in[3];
    const void* scale = d_in[4];
    const void* rot   = d_in[5];
    const void* tran  = d_in[6];

    prep_sort_kernel<<<NG/16, 256, 0, stream>>>(pos, rgb, opa, quat, scale, rot, tran);
    raster_kernel<<<NPIX/64, 1024, 0, stream>>>(d_out, rot);
}